// Round 1
// baseline (24.319 us; speedup 1.0000x reference)
//
#include <hip/hip_runtime.h>

// Problem constants from reference:
//   top_k_index_sort: (B, 1, TOPK) int32, values in [0, T)
//   patch_feat: (B, T, N, C) f32
//   audio_feat: (B, T, C) f32
// Outputs (concat flat): out_patch (B, TOPK, N, C) then out_audio (B, TOPK, C)
#define B_    16
#define T_    64
#define N_    196
#define C_    512
#define TOPK_ 10

// Per-(b,k) float4 chunk sizes
#define PATCH4 (N_ * C_ / 4)   // 25088
#define AUD4   (C_ / 4)        // 128

__global__ void __launch_bounds__(256)
TopKSegsSelection_gather(const int* __restrict__ idx,
                         const float4* __restrict__ patch,
                         const float4* __restrict__ audio,
                         float4* __restrict__ out) {
    const int patch_total = B_ * TOPK_ * PATCH4;          // 4,014,080 float4
    const int total       = patch_total + B_ * TOPK_ * AUD4; // + 20,480

    int i = blockIdx.x * blockDim.x + threadIdx.x;
    if (i >= total) return;

    if (i < patch_total) {
        int bk  = i / PATCH4;             // (b*TOPK + k)
        int rem = i - bk * PATCH4;
        int b   = bk / TOPK_;
        int t   = idx[bk];                // top_k_index_sort[b,0,k]
        out[i] = patch[(size_t)(b * T_ + t) * PATCH4 + rem];
    } else {
        int j   = i - patch_total;
        int bk  = j / AUD4;
        int rem = j - bk * AUD4;
        int b   = bk / TOPK_;
        int t   = idx[bk];
        out[i] = audio[(size_t)(b * T_ + t) * AUD4 + rem];
    }
}

extern "C" void kernel_launch(void* const* d_in, const int* in_sizes, int n_in,
                              void* d_out, int out_size, void* d_ws, size_t ws_size,
                              hipStream_t stream) {
    const int*    idx   = (const int*)d_in[0];
    const float4* patch = (const float4*)d_in[1];
    const float4* audio = (const float4*)d_in[2];
    float4*       out   = (float4*)d_out;

    const int total = B_ * TOPK_ * PATCH4 + B_ * TOPK_ * AUD4;
    const int block = 256;
    const int grid  = (total + block - 1) / block;

    TopKSegsSelection_gather<<<grid, block, 0, stream>>>(idx, patch, audio, out);
}